// Round 8
// baseline (10385.255 us; speedup 1.0000x reference)
//
#include <hip/hip_runtime.h>
#include <hip/hip_cooperative_groups.h>
#include <math.h>

#define VV 32000
#define EE 256
#define HH 512
#define SS 400
#define TT 100
#define BB 32
#define NBLK 128

// ---- workspace layout (float offsets) ----
#define WS_HPP   0u                        // 2 * 32*512 (h ping-pong)
#define WS_ARR   32768u                    // 500 steps x 8 lines x 64-int stride
#define WS_HALL  288768u                   // 100*32*512
#define WS_OE    (288768u + 1638400u)      // 3200*256
#define WS_M     (WS_OE + 819200u)         // 125*3200
#define WS_ZZ    (WS_M + 400000u)
#define WS_AM    (WS_ZZ + 400000u)
#define WS_GOLD  (WS_AM + 400000u)
#define WS_NLL   (WS_GOLD + 3200u)

__global__ __launch_bounds__(256) void k_zero(float* p, int n) {
    int i = blockIdx.x * 256 + threadIdx.x;
    if (i < n) p[i] = 0.f;
}

__device__ __forceinline__ float dot4(float4 a, float4 b) {
    return a.x * b.x + a.y * b.y + a.z * b.z + a.w * b.w;
}

// x-projection (gi) for step snext: partials + 32-lane butterfly; w==0 lanes
// write gi_buf. h-independent -> fills the barrier-wait window.
__device__ __forceinline__ void gi_compute(
    const float* __restrict__ emb, const int* __restrict__ src, const int* __restrict__ tgt,
    int phase, int snext, const float4* __restrict__ Ws4,
    float (*gi_buf)[3][4][4], int w, int bq, int b0)
{
    float acc[3][4][4];
    #pragma unroll
    for (int g = 0; g < 3; ++g)
        #pragma unroll
        for (int c = 0; c < 4; ++c)
            #pragma unroll
            for (int i = 0; i < 4; ++i) acc[g][c][i] = 0.f;
    float4 x0[4], x1[4];
    #pragma unroll
    for (int i = 0; i < 4; ++i) {
        int tk = phase ? (snext ? tgt[(snext - 1) * BB + b0 + i] : 1) : src[snext * BB + b0 + i];
        const float* xr = emb + (size_t)tk * EE + w * 4;
        x0[i] = *(const float4*)xr;
        x1[i] = *(const float4*)(xr + 128);
    }
    #pragma unroll
    for (int g = 0; g < 3; ++g)
        #pragma unroll
        for (int c = 0; c < 4; ++c) {
            float4 w0 = Ws4[(g * 4 + c) * 193 + w];
            float4 w1 = Ws4[(g * 4 + c) * 193 + w + 32];
            #pragma unroll
            for (int i = 0; i < 4; ++i)
                acc[g][c][i] += dot4(x0[i], w0) + dot4(x1[i], w1);
        }
    #pragma unroll
    for (int m = 1; m <= 16; m <<= 1)
        #pragma unroll
        for (int g = 0; g < 3; ++g)
            #pragma unroll
            for (int c = 0; c < 4; ++c)
                #pragma unroll
                for (int i = 0; i < 4; ++i)
                    acc[g][c][i] += __shfl_xor(acc[g][c][i], m);
    if (w == 0)
        #pragma unroll
        for (int g = 0; g < 3; ++g)
            #pragma unroll
            for (int c = 0; c < 4; ++c)
                *(float4*)&gi_buf[bq][g][c][0] =
                    make_float4(acc[g][c][0], acc[g][c][1], acc[g][c][2], acc[g][c][3]);
}

// ==================== persistent recurrence, wide coherent loads ====================
// 128 blocks x 256 threads (coop). Block owns 4 h-cols; weights LDS-resident.
// h loads via inline-asm global_load_dwordx4 sc0 sc1 (IC-coherent, 16B/request):
// 4x fewer coherent requests than dword atomics. Stores: scalar coherent
// (LLVM can't take float4 as asm input operand).
__global__ __launch_bounds__(256, 1) void k_rec4(
    const float* __restrict__ emb, const int* __restrict__ src, const int* __restrict__ tgt,
    const float* __restrict__ eWih, const float* __restrict__ eWhh,
    const float* __restrict__ ebih, const float* __restrict__ ebhh,
    const float* __restrict__ dWih, const float* __restrict__ dWhh,
    const float* __restrict__ dbih, const float* __restrict__ dbhh,
    float* __restrict__ hpp, float* __restrict__ Hall, int* __restrict__ arr)
{
    __shared__ float4 Ws4[12 * 193];
    __shared__ __align__(16) float gi_buf[8][3][4][4];   // [bq][g: r,z,nx][c][i]
    __shared__ __align__(16) float gh_buf[8][3][4][4];   // [bq][g: r,z,nh][c][i]
    __shared__ float4 hp_s[32];                          // hprev[b][cg0..cg0+3]
    __shared__ float bias_s[4][4];                       // [q: r,z,nx,nh][c]
    const int tid = threadIdx.x;
    const int w   = tid & 31;
    const int bq  = tid >> 5;
    const int b0  = bq * 4;
    const int cg0 = blockIdx.x * 4;
    const int myline = (blockIdx.x & 7) * 64;
    const int wsel = blockIdx.x & 31;    // lane-w that holds this block's hp f4
    const int jsel = blockIdx.x >> 5;    // jh index of that f4

    int s = 0;
    for (int phase = 0; phase < 2; ++phase) {
        const float* Wih = phase ? dWih : eWih;
        const float* Whh = phase ? dWhh : eWhh;
        const float* bih = phase ? dbih : ebih;
        const float* bhh = phase ? dbhh : ebhh;

        for (int u = tid; u < 12 * 192; u += 256) {
            int r = u / 192, q = u - r * 192;
            int g = r >> 2, c = r & 3;
            size_t row = (size_t)(g * HH + cg0 + c);
            float4 v;
            if (q < 64) v = *(const float4*)(Wih + row * EE + q * 4);
            else        v = *(const float4*)(Whh + row * HH + (q - 64) * 4);
            Ws4[r * 193 + q] = v;
        }
        if (tid < 4) {
            int cg = cg0 + tid;
            bias_s[0][tid] = bih[cg] + bhh[cg];
            bias_s[1][tid] = bih[HH + cg] + bhh[HH + cg];
            bias_s[2][tid] = bih[2 * HH + cg];
            bias_s[3][tid] = bhh[2 * HH + cg];
        }
        __syncthreads();

        gi_compute(emb, src, tgt, phase, 0, Ws4, gi_buf, w, bq, b0);
        __syncthreads();

        const int T = phase ? TT : SS;
        for (int t = 0; t < T; ++t, ++s) {
            const float* hprev; float* hnext;
            if (phase == 0) {
                hprev = hpp + (t & 1) * (BB * HH);
                hnext = hpp + ((t + 1) & 1) * (BB * HH);
            } else {
                hprev = t ? (Hall + (size_t)(t - 1) * (BB * HH)) : hpp;
                hnext = Hall + (size_t)t * (BB * HH);
            }

            // ---- coherent wide h load: 16 dwordx4 in flight, one waitcnt ----
            float4 hf[4][4];
            const float* p0 = hprev + (b0 + 0) * HH + w * 4;
            const float* p1 = hprev + (b0 + 1) * HH + w * 4;
            const float* p2 = hprev + (b0 + 2) * HH + w * 4;
            const float* p3 = hprev + (b0 + 3) * HH + w * 4;
            asm volatile(
                "global_load_dwordx4 %0, %16, off sc0 sc1\n\t"
                "global_load_dwordx4 %1, %16, off offset:512 sc0 sc1\n\t"
                "global_load_dwordx4 %2, %16, off offset:1024 sc0 sc1\n\t"
                "global_load_dwordx4 %3, %16, off offset:1536 sc0 sc1\n\t"
                "global_load_dwordx4 %4, %17, off sc0 sc1\n\t"
                "global_load_dwordx4 %5, %17, off offset:512 sc0 sc1\n\t"
                "global_load_dwordx4 %6, %17, off offset:1024 sc0 sc1\n\t"
                "global_load_dwordx4 %7, %17, off offset:1536 sc0 sc1\n\t"
                "global_load_dwordx4 %8, %18, off sc0 sc1\n\t"
                "global_load_dwordx4 %9, %18, off offset:512 sc0 sc1\n\t"
                "global_load_dwordx4 %10, %18, off offset:1024 sc0 sc1\n\t"
                "global_load_dwordx4 %11, %18, off offset:1536 sc0 sc1\n\t"
                "global_load_dwordx4 %12, %19, off sc0 sc1\n\t"
                "global_load_dwordx4 %13, %19, off offset:512 sc0 sc1\n\t"
                "global_load_dwordx4 %14, %19, off offset:1024 sc0 sc1\n\t"
                "global_load_dwordx4 %15, %19, off offset:1536 sc0 sc1\n\t"
                "s_waitcnt vmcnt(0)"
                : "=&v"(hf[0][0]), "=&v"(hf[0][1]), "=&v"(hf[0][2]), "=&v"(hf[0][3]),
                  "=&v"(hf[1][0]), "=&v"(hf[1][1]), "=&v"(hf[1][2]), "=&v"(hf[1][3]),
                  "=&v"(hf[2][0]), "=&v"(hf[2][1]), "=&v"(hf[2][2]), "=&v"(hf[2][3]),
                  "=&v"(hf[3][0]), "=&v"(hf[3][1]), "=&v"(hf[3][2]), "=&v"(hf[3][3])
                : "v"(p0), "v"(p1), "v"(p2), "v"(p3)
                : "memory");

            // stash this block's hp f4 (hprev[b][cg0..3]) for the epilogue
            if (w == wsel) {
                #pragma unroll
                for (int i = 0; i < 4; ++i) {
                    float4 v = (jsel == 0) ? hf[i][0] : (jsel == 1) ? hf[i][1]
                             : (jsel == 2) ? hf[i][2] : hf[i][3];
                    hp_s[b0 + i] = v;
                }
            }

            // ---- gh = W_hh @ h_prev ----
            float ah[3][4][4];
            #pragma unroll
            for (int g = 0; g < 3; ++g)
                #pragma unroll
                for (int c = 0; c < 4; ++c)
                    #pragma unroll
                    for (int i = 0; i < 4; ++i) ah[g][c][i] = 0.f;
            #pragma unroll
            for (int jh = 0; jh < 4; ++jh)
                #pragma unroll
                for (int g = 0; g < 3; ++g)
                    #pragma unroll
                    for (int c = 0; c < 4; ++c) {
                        float4 wv = Ws4[(g * 4 + c) * 193 + 64 + w + 32 * jh];
                        #pragma unroll
                        for (int i = 0; i < 4; ++i)
                            ah[g][c][i] += dot4(hf[i][jh], wv);
                    }
            #pragma unroll
            for (int m = 1; m <= 16; m <<= 1)
                #pragma unroll
                for (int g = 0; g < 3; ++g)
                    #pragma unroll
                    for (int c = 0; c < 4; ++c)
                        #pragma unroll
                        for (int i = 0; i < 4; ++i)
                            ah[g][c][i] += __shfl_xor(ah[g][c][i], m);
            if (w == 0)
                #pragma unroll
                for (int g = 0; g < 3; ++g)
                    #pragma unroll
                    for (int c = 0; c < 4; ++c)
                        *(float4*)&gh_buf[bq][g][c][0] =
                            make_float4(ah[g][c][0], ah[g][c][1], ah[g][c][2], ah[g][c][3]);
            __syncthreads();

            // ---- activation: 32 threads, one batch row each, coherent stores ----
            if (tid < 32) {
                int b = tid, bq2 = b >> 2, i2 = b & 3;
                float4 hp = hp_s[b];
                float o[4];
                #pragma unroll
                for (int c = 0; c < 4; ++c) {
                    float gr  = gi_buf[bq2][0][c][i2] + gh_buf[bq2][0][c][i2] + bias_s[0][c];
                    float gz  = gi_buf[bq2][1][c][i2] + gh_buf[bq2][1][c][i2] + bias_s[1][c];
                    float gnx = gi_buf[bq2][2][c][i2] + bias_s[2][c];
                    float gnh = gh_buf[bq2][2][c][i2] + bias_s[3][c];
                    float r = 1.f / (1.f + expf(-gr));
                    float z = 1.f / (1.f + expf(-gz));
                    float n = tanhf(gnx + r * gnh);
                    float hpc = (c == 0) ? hp.x : (c == 1) ? hp.y : (c == 2) ? hp.z : hp.w;
                    o[c] = (1.f - z) * n + z * hpc;
                }
                float* hq = hnext + b * HH + cg0;
                __hip_atomic_store(hq + 0, o[0], __ATOMIC_RELAXED, __HIP_MEMORY_SCOPE_AGENT);
                __hip_atomic_store(hq + 1, o[1], __ATOMIC_RELAXED, __HIP_MEMORY_SCOPE_AGENT);
                __hip_atomic_store(hq + 2, o[2], __ATOMIC_RELAXED, __HIP_MEMORY_SCOPE_AGENT);
                __hip_atomic_store(hq + 3, o[3], __ATOMIC_RELAXED, __HIP_MEMORY_SCOPE_AGENT);
            }
            __builtin_amdgcn_s_waitcnt(0);   // stores at the coherence point
            __syncthreads();

            // ---- arrive (8 distributed lines) ----
            if (tid == 0)
                __hip_atomic_fetch_add(arr + (size_t)s * 512 + myline, 1,
                                       __ATOMIC_RELAXED, __HIP_MEMORY_SCOPE_AGENT);

            // ---- overlap: gi for next step ----
            if (t < T - 1)
                gi_compute(emb, src, tgt, phase, t + 1, Ws4, gi_buf, w, bq, b0);

            // ---- wait: wave0 parallel-polls the 8 lines ----
            if (tid < 64) {
                const int* base = arr + (size_t)s * 512;
                for (;;) {
                    int v = 0;
                    if (tid < 8)
                        v = __hip_atomic_load(base + tid * 64,
                                              __ATOMIC_RELAXED, __HIP_MEMORY_SCOPE_AGENT);
                    v += __shfl_xor(v, 1);
                    v += __shfl_xor(v, 2);
                    v += __shfl_xor(v, 4);
                    if (__shfl(v, 0) == NBLK) break;
                    __builtin_amdgcn_s_sleep(1);
                }
            }
            __syncthreads();
        }
    }
}

// ==================== R1-proven fallback (per-step launches) ====================
__device__ __forceinline__ void gru_step_body(
    const float* __restrict__ emb, const int* __restrict__ tok, int sos,
    const float* __restrict__ Wih, const float* __restrict__ Whh,
    const float* __restrict__ bih, const float* __restrict__ bhh,
    const float* __restrict__ h_in, float* __restrict__ h_out,
    float (*z)[772], float (*part)[3][16][16],
    int tid, int cblk, int bg0)
{
    #pragma unroll
    for (int i = 0; i < 4; ++i) {
        int idx = tid + i * 768;
        if (idx < 1024) {
            int bl = idx >> 6, k4 = idx & 63;
            int tk = sos ? 1 : tok[bg0 + bl];
            *(float4*)&z[bl][k4 * 4] = *(const float4*)(emb + (size_t)tk * EE + k4 * 4);
        } else {
            int j = idx - 1024;
            int bl = j >> 7, k4 = j & 127;
            *(float4*)&z[bl][256 + k4 * 4] = *(const float4*)(h_in + (bg0 + bl) * HH + k4 * 4);
        }
    }
    __syncthreads();
    const int b  = tid & 15;
    const int c  = (tid >> 4) & 15;
    const int kp = tid >> 8;
    const int cg = cblk * 16 + c;
    const float *w0, *w1, *w2; int koff;
    if (kp == 0) {
        w0 = Wih + (size_t)(0 * HH + cg) * EE;
        w1 = Wih + (size_t)(1 * HH + cg) * EE;
        w2 = Wih + (size_t)(2 * HH + cg) * EE;
        koff = 0;
    } else {
        int o = (kp == 1) ? 0 : 256;
        w0 = Whh + (size_t)(0 * HH + cg) * HH + o;
        w1 = Whh + (size_t)(1 * HH + cg) * HH + o;
        w2 = Whh + (size_t)(2 * HH + cg) * HH + o;
        koff = 256 + o;
    }
    float a0 = 0.f, a1 = 0.f, a2 = 0.f;
    #pragma unroll 8
    for (int k4 = 0; k4 < 64; ++k4) {
        float4 zv = *(const float4*)&z[b][koff + k4 * 4];
        float4 v0 = *(const float4*)(w0 + k4 * 4);
        float4 v1 = *(const float4*)(w1 + k4 * 4);
        float4 v2 = *(const float4*)(w2 + k4 * 4);
        a0 += zv.x * v0.x + zv.y * v0.y + zv.z * v0.z + zv.w * v0.w;
        a1 += zv.x * v1.x + zv.y * v1.y + zv.z * v1.z + zv.w * v1.w;
        a2 += zv.x * v2.x + zv.y * v2.y + zv.z * v2.z + zv.w * v2.w;
    }
    part[kp][0][c][b] = a0;
    part[kp][1][c][b] = a1;
    part[kp][2][c][b] = a2;
    __syncthreads();
    if (kp == 0) {
        float gr  = part[0][0][c][b] + part[1][0][c][b] + part[2][0][c][b];
        float gz  = part[0][1][c][b] + part[1][1][c][b] + part[2][1][c][b];
        float gin = part[0][2][c][b];
        float ghn = part[1][2][c][b] + part[2][2][c][b];
        float r  = 1.f / (1.f + expf(-(gr + bih[cg] + bhh[cg])));
        float zg = 1.f / (1.f + expf(-(gz + bih[HH + cg] + bhh[HH + cg])));
        float n  = tanhf(gin + bih[2 * HH + cg] + r * (ghn + bhh[2 * HH + cg]));
        float hp = z[b][256 + cg];
        h_out[(bg0 + b) * HH + cg] = (1.f - zg) * n + zg * hp;
    }
}

__global__ __launch_bounds__(768) void k_gru(
    const float* __restrict__ emb, const int* __restrict__ tok, int sos,
    const float* __restrict__ Wih, const float* __restrict__ Whh,
    const float* __restrict__ bih, const float* __restrict__ bhh,
    const float* __restrict__ h_in, float* __restrict__ h_out)
{
    __shared__ float z[16][772];
    __shared__ float part[3][3][16][16];
    gru_step_body(emb, tok, sos, Wih, Whh, bih, bhh, h_in, h_out,
                  z, part, threadIdx.x, blockIdx.x & 31, (blockIdx.x >> 5) * 16);
}

// ==================== output path (unchanged) ====================
__global__ __launch_bounds__(256) void k_outemb(
    const float* __restrict__ Hall, const float* __restrict__ preW,
    const float* __restrict__ preb, float* __restrict__ OE)
{
    __shared__ float hs[16][516];
    const int tid = threadIdx.x;
    const int c0 = blockIdx.x * 64;
    const int r0 = blockIdx.y * 16;
    #pragma unroll
    for (int i = 0; i < 8; ++i) {
        int idx = tid + i * 256;
        int rr = idx >> 7, k4 = idx & 127;
        *(float4*)&hs[rr][k4 * 4] = *(const float4*)(Hall + (size_t)(r0 + rr) * HH + k4 * 4);
    }
    __syncthreads();
    const int rr = tid & 15, cc = tid >> 4;
    int cj[4]; float acc[4];
    #pragma unroll
    for (int j = 0; j < 4; ++j) { cj[j] = c0 + cc + 16 * j; acc[j] = preb[cj[j]]; }
    for (int k4 = 0; k4 < 128; ++k4) {
        float4 hv = *(const float4*)&hs[rr][k4 * 4];
        #pragma unroll
        for (int j = 0; j < 4; ++j) {
            float4 wv = *(const float4*)(preW + (size_t)cj[j] * HH + k4 * 4);
            acc[j] += hv.x * wv.x + hv.y * wv.y + hv.z * wv.z + hv.w * wv.w;
        }
    }
    #pragma unroll
    for (int j = 0; j < 4; ++j) OE[(size_t)(r0 + rr) * EE + cj[j]] = acc[j];
}

__global__ __launch_bounds__(128) void k_logits(
    const float* __restrict__ OE, const float* __restrict__ emb,
    const float* __restrict__ outb, const int* __restrict__ tgt,
    float* __restrict__ m_arr, float* __restrict__ z_arr,
    unsigned int* __restrict__ am_arr, float* __restrict__ gold_arr)
{
    __shared__ float oes[32][260];
    __shared__ float ems[256][18];
    const int tid = threadIdx.x;
    const int c0 = blockIdx.x * 256;
    const int r0 = blockIdx.y * 32;

    #pragma unroll
    for (int i = 0; i < 16; ++i) {
        int idx = tid + i * 128;
        int rr2 = idx >> 6, k4 = idx & 63;
        *(float4*)&oes[rr2][k4 * 4] = *(const float4*)(OE + (size_t)(r0 + rr2) * EE + k4 * 4);
    }

    const int rr  = tid >> 5;
    const int ccg = tid & 31;
    float acc[8][8];
    #pragma unroll
    for (int i = 0; i < 8; ++i)
        #pragma unroll
        for (int j = 0; j < 8; ++j) acc[i][j] = 0.f;

    for (int kc = 0; kc < 16; ++kc) {
        __syncthreads();
        #pragma unroll
        for (int i = 0; i < 16; ++i) {
            int idx = tid + i * 128;
            int col = idx >> 3, f2 = idx & 7;
            *(float2*)&ems[col][f2 * 2] =
                *(const float2*)(emb + (size_t)(c0 + col) * EE + kc * 16 + f2 * 2);
        }
        __syncthreads();
        #pragma unroll
        for (int kk = 0; kk < 16; kk += 4) {
            float4 ov[8];
            #pragma unroll
            for (int i = 0; i < 8; ++i) ov[i] = *(const float4*)&oes[rr * 8 + i][kc * 16 + kk];
            #pragma unroll
            for (int j = 0; j < 8; ++j) {
                float2 e0 = *(const float2*)&ems[ccg + 32 * j][kk];
                float2 e1 = *(const float2*)&ems[ccg + 32 * j][kk + 2];
                #pragma unroll
                for (int i = 0; i < 8; ++i)
                    acc[i][j] += ov[i].x * e0.x + ov[i].y * e0.y + ov[i].z * e1.x + ov[i].w * e1.y;
            }
        }
    }

    #pragma unroll
    for (int i = 0; i < 8; ++i) {
        int r = r0 + rr * 8 + i;
        int gold = tgt[r];
        float vals[8]; float m = -3.4e38f; int cb = 0x7fffffff;
        #pragma unroll
        for (int j = 0; j < 8; ++j) {
            int cj = c0 + ccg + 32 * j;
            float v = acc[i][j] + outb[cj];
            vals[j] = v;
            if (v > m) { m = v; cb = cj; }
            if (cj == gold) gold_arr[r] = v;
        }
        for (int mk = 1; mk <= 16; mk <<= 1) {
            float mo = __shfl_xor(m, mk);
            int   co = __shfl_xor(cb, mk);
            if (mo > m || (mo == m && co < cb)) { m = mo; cb = co; }
        }
        float s = 0.f;
        #pragma unroll
        for (int j = 0; j < 8; ++j) s += expf(vals[j] - m);
        for (int mk = 1; mk <= 16; mk <<= 1) s += __shfl_xor(s, mk);
        if (ccg == 0) {
            size_t p = (size_t)blockIdx.x * 3200 + r;
            m_arr[p] = m; z_arr[p] = s; am_arr[p] = (unsigned)cb;
        }
    }
}

__global__ __launch_bounds__(256) void k_merge(
    const float* __restrict__ m_arr, const float* __restrict__ z_arr,
    const unsigned* __restrict__ am_arr, const float* __restrict__ gold_arr,
    float* __restrict__ nll, float* __restrict__ out)
{
    int r = blockIdx.x * 256 + threadIdx.x;
    if (r >= 3200) return;
    float M = -3.4e38f, Z = 0.f, bm = -3.4e38f; unsigned bc = 0u;
    for (int s = 0; s < 125; ++s) {
        size_t p = (size_t)s * 3200 + r;
        float ms = m_arr[p]; float zs = z_arr[p]; unsigned cs = am_arr[p];
        if (ms > M) { Z = Z * expf(M - ms) + zs; M = ms; }
        else        { Z += zs * expf(ms - M); }
        if (ms > bm || (ms == bm && cs < bc)) { bm = ms; bc = cs; }
    }
    float pg = expf(gold_arr[r] - M) / Z;
    nll[r] = -logf(pg + 1e-20f);
    out[r] = (float)bc;
}

__global__ __launch_bounds__(128) void k_loss(
    const float* __restrict__ nll, const int* __restrict__ tgt, float* __restrict__ out)
{
    __shared__ float ls[128];
    int t = threadIdx.x;
    float lt = 0.f;
    if (t < TT) {
        float s = 0.f; int cnt = 0;
        for (int b = 0; b < BB; ++b) {
            int g = tgt[t * BB + b];
            if (g != 0) { s += nll[t * BB + b]; cnt++; }
        }
        lt = s / fmaxf((float)cnt, 1.f);
    }
    ls[t] = lt;
    __syncthreads();
    for (int off = 64; off > 0; off >>= 1) {
        if (t < off) ls[t] += ls[t + off];
        __syncthreads();
    }
    if (t == 0) out[3200] = ls[0];
}

extern "C" void kernel_launch(void* const* d_in, const int* in_sizes, int n_in,
                              void* d_out, int out_size, void* d_ws, size_t ws_size,
                              hipStream_t stream) {
    const int*   src  = (const int*)  d_in[0];
    const int*   tgt  = (const int*)  d_in[1];
    const float* emb  = (const float*)d_in[2];
    const float* eWih = (const float*)d_in[3];
    const float* eWhh = (const float*)d_in[4];
    const float* ebih = (const float*)d_in[5];
    const float* ebhh = (const float*)d_in[6];
    const float* dWih = (const float*)d_in[7];
    const float* dWhh = (const float*)d_in[8];
    const float* dbih = (const float*)d_in[9];
    const float* dbhh = (const float*)d_in[10];
    const float* preW = (const float*)d_in[11];
    const float* preb = (const float*)d_in[12];
    const float* outb = (const float*)d_in[13];

    float* ws   = (float*)d_ws;
    float* out  = (float*)d_out;
    float* hpp  = ws + WS_HPP;
    int*   arr  = (int*)(ws + WS_ARR);
    float* Hall = ws + WS_HALL;
    float* OE   = ws + WS_OE;
    float* m_a  = ws + WS_M;
    float* z_a  = ws + WS_ZZ;
    unsigned* am_a = (unsigned*)(ws + WS_AM);
    float* gold = ws + WS_GOLD;
    float* nll  = ws + WS_NLL;

    // zero h0 + all barrier counter lines
    k_zero<<<1128, 256, 0, stream>>>(ws, 288768);

    hipError_t coop_err;
    {
        const float* emb_ = emb; const int* src_ = src; const int* tgt_ = tgt;
        const float* a3 = eWih; const float* a4 = eWhh; const float* a5 = ebih; const float* a6 = ebhh;
        const float* a7 = dWih; const float* a8 = dWhh; const float* a9 = dbih; const float* a10 = dbhh;
        float* hpp_ = hpp; float* Hall_ = Hall; int* arr_ = arr;
        void* args[] = { (void*)&emb_, (void*)&src_, (void*)&tgt_,
                         (void*)&a3, (void*)&a4, (void*)&a5, (void*)&a6,
                         (void*)&a7, (void*)&a8, (void*)&a9, (void*)&a10,
                         (void*)&hpp_, (void*)&Hall_, (void*)&arr_ };
        coop_err = hipLaunchCooperativeKernel((const void*)k_rec4, dim3(NBLK), dim3(256),
                                              args, 0, stream);
    }
    if (coop_err != hipSuccess) {
        for (int t = 0; t < SS; ++t) {
            const float* hin = hpp + (t & 1) * (BB * HH);
            float* hout      = hpp + ((t + 1) & 1) * (BB * HH);
            k_gru<<<64, 768, 0, stream>>>(emb, src + t * BB, 0,
                                          eWih, eWhh, ebih, ebhh, hin, hout);
        }
        for (int t = 0; t < TT; ++t) {
            const float* hin = (t == 0) ? hpp : (Hall + (size_t)(t - 1) * BB * HH);
            float* hout      = Hall + (size_t)t * BB * HH;
            const int* tp    = (t == 0) ? src : (tgt + (t - 1) * BB);
            k_gru<<<64, 768, 0, stream>>>(emb, tp, (t == 0) ? 1 : 0,
                                          dWih, dWhh, dbih, dbhh, hin, hout);
        }
    }

    k_outemb<<<dim3(4, 200), 256, 0, stream>>>(Hall, preW, preb, OE);
    k_logits<<<dim3(125, 100), 128, 0, stream>>>(OE, emb, outb, tgt, m_a, z_a, am_a, gold);
    k_merge<<<13, 256, 0, stream>>>(m_a, z_a, am_a, gold, nll, out);
    k_loss<<<1, 128, 0, stream>>>(nll, tgt, out);
}

// Round 9
// 7615.210 us; speedup vs baseline: 1.3638x; 1.3638x over previous
//
#include <hip/hip_runtime.h>
#include <hip/hip_cooperative_groups.h>
#include <math.h>

#define VV 32000
#define EE 256
#define HH 512
#define SS 400
#define TT 100
#define BB 32
#define NBLK 128

// ---- workspace layout (float offsets) ----
#define WS_HPP   0u                        // 2 * 32*512 (h ping-pong)
#define WS_ARR   32768u                    // 500 steps x 8 lines x 64-int stride
#define WS_HALL  288768u                   // 100*32*512
#define WS_OE    (288768u + 1638400u)      // 3200*256
#define WS_M     (WS_OE + 819200u)         // 125*3200
#define WS_ZZ    (WS_M + 400000u)
#define WS_AM    (WS_ZZ + 400000u)
#define WS_GOLD  (WS_AM + 400000u)
#define WS_NLL   (WS_GOLD + 3200u)

__global__ __launch_bounds__(256) void k_zero(float* p, int n) {
    int i = blockIdx.x * 256 + threadIdx.x;
    if (i < n) p[i] = 0.f;
}

__device__ __forceinline__ float dot4(float4 a, float4 b) {
    return a.x * b.x + a.y * b.y + a.z * b.z + a.w * b.w;
}

// Coherent (MALL-level) float4 load as 2 x uint64 relaxed AGENT atomic loads:
// compiler emits the correct agent-scope cache bits (IC-coherent, not system),
// and 8B/request halves the IC request count vs dword loads.
__device__ __forceinline__ float4 ld4_coh(const float* p) {
    const unsigned long long* q = (const unsigned long long*)p;
    unsigned long long a = __hip_atomic_load(q + 0, __ATOMIC_RELAXED, __HIP_MEMORY_SCOPE_AGENT);
    unsigned long long b = __hip_atomic_load(q + 1, __ATOMIC_RELAXED, __HIP_MEMORY_SCOPE_AGENT);
    float4 v;
    v.x = __uint_as_float((unsigned)(a & 0xffffffffull));
    v.y = __uint_as_float((unsigned)(a >> 32));
    v.z = __uint_as_float((unsigned)(b & 0xffffffffull));
    v.w = __uint_as_float((unsigned)(b >> 32));
    return v;
}

// x-projection (gi) for step snext: partials + 32-lane butterfly; w==0 lanes
// write gi_buf. h-independent -> fills the barrier-wait window.
__device__ __forceinline__ void gi_compute(
    const float* __restrict__ emb, const int* __restrict__ src, const int* __restrict__ tgt,
    int phase, int snext, const float4* __restrict__ Ws4,
    float (*gi_buf)[3][4][4], int w, int bq, int b0)
{
    float acc[3][4][4];
    #pragma unroll
    for (int g = 0; g < 3; ++g)
        #pragma unroll
        for (int c = 0; c < 4; ++c)
            #pragma unroll
            for (int i = 0; i < 4; ++i) acc[g][c][i] = 0.f;
    float4 x0[4], x1[4];
    #pragma unroll
    for (int i = 0; i < 4; ++i) {
        int tk = phase ? (snext ? tgt[(snext - 1) * BB + b0 + i] : 1) : src[snext * BB + b0 + i];
        const float* xr = emb + (size_t)tk * EE + w * 4;
        x0[i] = *(const float4*)xr;
        x1[i] = *(const float4*)(xr + 128);
    }
    #pragma unroll
    for (int g = 0; g < 3; ++g)
        #pragma unroll
        for (int c = 0; c < 4; ++c) {
            float4 w0 = Ws4[(g * 4 + c) * 193 + w];
            float4 w1 = Ws4[(g * 4 + c) * 193 + w + 32];
            #pragma unroll
            for (int i = 0; i < 4; ++i)
                acc[g][c][i] += dot4(x0[i], w0) + dot4(x1[i], w1);
        }
    #pragma unroll
    for (int m = 1; m <= 16; m <<= 1)
        #pragma unroll
        for (int g = 0; g < 3; ++g)
            #pragma unroll
            for (int c = 0; c < 4; ++c)
                #pragma unroll
                for (int i = 0; i < 4; ++i)
                    acc[g][c][i] += __shfl_xor(acc[g][c][i], m);
    if (w == 0)
        #pragma unroll
        for (int g = 0; g < 3; ++g)
            #pragma unroll
            for (int c = 0; c < 4; ++c)
                *(float4*)&gi_buf[bq][g][c][0] =
                    make_float4(acc[g][c][0], acc[g][c][1], acc[g][c][2], acc[g][c][3]);
}

// ==================== persistent recurrence (R6 structure, uint64 loads) ====================
__global__ __launch_bounds__(256, 1) void k_rec5(
    const float* __restrict__ emb, const int* __restrict__ src, const int* __restrict__ tgt,
    const float* __restrict__ eWih, const float* __restrict__ eWhh,
    const float* __restrict__ ebih, const float* __restrict__ ebhh,
    const float* __restrict__ dWih, const float* __restrict__ dWhh,
    const float* __restrict__ dbih, const float* __restrict__ dbhh,
    float* __restrict__ hpp, float* __restrict__ Hall, int* __restrict__ arr)
{
    __shared__ float4 Ws4[12 * 193];
    __shared__ __align__(16) float gi_buf[8][3][4][4];   // [bq][g: r,z,nx][c][i]
    __shared__ __align__(16) float gh_buf[8][3][4][4];   // [bq][g: r,z,nh][c][i]
    const int tid = threadIdx.x;
    const int w   = tid & 31;
    const int bq  = tid >> 5;
    const int b0  = bq * 4;
    const int cg0 = blockIdx.x * 4;
    const int myline = (blockIdx.x & 7) * 64;

    int s = 0;
    for (int phase = 0; phase < 2; ++phase) {
        const float* Wih = phase ? dWih : eWih;
        const float* Whh = phase ? dWhh : eWhh;
        const float* bih = phase ? dbih : ebih;
        const float* bhh = phase ? dbhh : ebhh;

        for (int u = tid; u < 12 * 192; u += 256) {
            int r = u / 192, q = u - r * 192;
            int g = r >> 2, c = r & 3;
            size_t row = (size_t)(g * HH + cg0 + c);
            float4 v;
            if (q < 64) v = *(const float4*)(Wih + row * EE + q * 4);
            else        v = *(const float4*)(Whh + row * HH + (q - 64) * 4);
            Ws4[r * 193 + q] = v;
        }
        float br_ = 0.f, bz_ = 0.f, bnx_ = 0.f, bnh_ = 0.f;
        if (tid < 128) {
            int cg = cg0 + (tid & 3);
            br_  = bih[cg] + bhh[cg];
            bz_  = bih[HH + cg] + bhh[HH + cg];
            bnx_ = bih[2 * HH + cg];
            bnh_ = bhh[2 * HH + cg];
        }
        __syncthreads();

        gi_compute(emb, src, tgt, phase, 0, Ws4, gi_buf, w, bq, b0);
        __syncthreads();

        const int T = phase ? TT : SS;
        for (int t = 0; t < T; ++t, ++s) {
            const float* hprev; float* hnext;
            if (phase == 0) {
                hprev = hpp + (t & 1) * (BB * HH);
                hnext = hpp + ((t + 1) & 1) * (BB * HH);
            } else {
                hprev = t ? (Hall + (size_t)(t - 1) * (BB * HH)) : hpp;
                hnext = Hall + (size_t)t * (BB * HH);
            }

            // ---- gh = W_hh @ h_prev (critical path) ----
            float4 hf[4][4];
            #pragma unroll
            for (int i = 0; i < 4; ++i) {
                const float* hr = hprev + (b0 + i) * HH + w * 4;
                #pragma unroll
                for (int jh = 0; jh < 4; ++jh) hf[i][jh] = ld4_coh(hr + jh * 128);
            }
            float ah[3][4][4];
            #pragma unroll
            for (int g = 0; g < 3; ++g)
                #pragma unroll
                for (int c = 0; c < 4; ++c)
                    #pragma unroll
                    for (int i = 0; i < 4; ++i) ah[g][c][i] = 0.f;
            #pragma unroll
            for (int jh = 0; jh < 4; ++jh)
                #pragma unroll
                for (int g = 0; g < 3; ++g)
                    #pragma unroll
                    for (int c = 0; c < 4; ++c) {
                        float4 wv = Ws4[(g * 4 + c) * 193 + 64 + w + 32 * jh];
                        #pragma unroll
                        for (int i = 0; i < 4; ++i)
                            ah[g][c][i] += dot4(hf[i][jh], wv);
                    }
            #pragma unroll
            for (int m = 1; m <= 16; m <<= 1)
                #pragma unroll
                for (int g = 0; g < 3; ++g)
                    #pragma unroll
                    for (int c = 0; c < 4; ++c)
                        #pragma unroll
                        for (int i = 0; i < 4; ++i)
                            ah[g][c][i] += __shfl_xor(ah[g][c][i], m);
            if (w == 0)
                #pragma unroll
                for (int g = 0; g < 3; ++g)
                    #pragma unroll
                    for (int c = 0; c < 4; ++c)
                        *(float4*)&gh_buf[bq][g][c][0] =
                            make_float4(ah[g][c][0], ah[g][c][1], ah[g][c][2], ah[g][c][3]);
            __syncthreads();

            // ---- activation + coherent h store ----
            if (tid < 128) {
                int b = tid >> 2, c = tid & 3;
                int bq2 = b >> 2, i2 = b & 3;
                float gr  = gi_buf[bq2][0][c][i2] + gh_buf[bq2][0][c][i2] + br_;
                float gz  = gi_buf[bq2][1][c][i2] + gh_buf[bq2][1][c][i2] + bz_;
                float gnx = gi_buf[bq2][2][c][i2] + bnx_;
                float gnh = gh_buf[bq2][2][c][i2] + bnh_;
                float r = 1.f / (1.f + expf(-gr));
                float z = 1.f / (1.f + expf(-gz));
                float n = tanhf(gnx + r * gnh);
                float hp = __hip_atomic_load(hprev + b * HH + cg0 + c,
                                             __ATOMIC_RELAXED, __HIP_MEMORY_SCOPE_AGENT);
                __hip_atomic_store(hnext + b * HH + cg0 + c, (1.f - z) * n + z * hp,
                                   __ATOMIC_RELAXED, __HIP_MEMORY_SCOPE_AGENT);
            }
            __builtin_amdgcn_s_waitcnt(0);
            __syncthreads();

            // ---- arrive (8 distributed lines) ----
            if (tid == 0)
                __hip_atomic_fetch_add(arr + (size_t)s * 512 + myline, 1,
                                       __ATOMIC_RELAXED, __HIP_MEMORY_SCOPE_AGENT);

            // ---- overlap: gi for next step ----
            if (t < T - 1)
                gi_compute(emb, src, tgt, phase, t + 1, Ws4, gi_buf, w, bq, b0);

            // ---- wait: wave0 parallel-polls the 8 lines ----
            if (tid < 64) {
                const int* base = arr + (size_t)s * 512;
                for (;;) {
                    int v = 0;
                    if (tid < 8)
                        v = __hip_atomic_load(base + tid * 64,
                                              __ATOMIC_RELAXED, __HIP_MEMORY_SCOPE_AGENT);
                    v += __shfl_xor(v, 1);
                    v += __shfl_xor(v, 2);
                    v += __shfl_xor(v, 4);
                    if (__shfl(v, 0) == NBLK) break;
                    __builtin_amdgcn_s_sleep(1);
                }
            }
            __syncthreads();
        }
    }
}

// ==================== R1-proven fallback (per-step launches) ====================
__device__ __forceinline__ void gru_step_body(
    const float* __restrict__ emb, const int* __restrict__ tok, int sos,
    const float* __restrict__ Wih, const float* __restrict__ Whh,
    const float* __restrict__ bih, const float* __restrict__ bhh,
    const float* __restrict__ h_in, float* __restrict__ h_out,
    float (*z)[772], float (*part)[3][16][16],
    int tid, int cblk, int bg0)
{
    #pragma unroll
    for (int i = 0; i < 4; ++i) {
        int idx = tid + i * 768;
        if (idx < 1024) {
            int bl = idx >> 6, k4 = idx & 63;
            int tk = sos ? 1 : tok[bg0 + bl];
            *(float4*)&z[bl][k4 * 4] = *(const float4*)(emb + (size_t)tk * EE + k4 * 4);
        } else {
            int j = idx - 1024;
            int bl = j >> 7, k4 = j & 127;
            *(float4*)&z[bl][256 + k4 * 4] = *(const float4*)(h_in + (bg0 + bl) * HH + k4 * 4);
        }
    }
    __syncthreads();
    const int b  = tid & 15;
    const int c  = (tid >> 4) & 15;
    const int kp = tid >> 8;
    const int cg = cblk * 16 + c;
    const float *w0, *w1, *w2; int koff;
    if (kp == 0) {
        w0 = Wih + (size_t)(0 * HH + cg) * EE;
        w1 = Wih + (size_t)(1 * HH + cg) * EE;
        w2 = Wih + (size_t)(2 * HH + cg) * EE;
        koff = 0;
    } else {
        int o = (kp == 1) ? 0 : 256;
        w0 = Whh + (size_t)(0 * HH + cg) * HH + o;
        w1 = Whh + (size_t)(1 * HH + cg) * HH + o;
        w2 = Whh + (size_t)(2 * HH + cg) * HH + o;
        koff = 256 + o;
    }
    float a0 = 0.f, a1 = 0.f, a2 = 0.f;
    #pragma unroll 8
    for (int k4 = 0; k4 < 64; ++k4) {
        float4 zv = *(const float4*)&z[b][koff + k4 * 4];
        float4 v0 = *(const float4*)(w0 + k4 * 4);
        float4 v1 = *(const float4*)(w1 + k4 * 4);
        float4 v2 = *(const float4*)(w2 + k4 * 4);
        a0 += zv.x * v0.x + zv.y * v0.y + zv.z * v0.z + zv.w * v0.w;
        a1 += zv.x * v1.x + zv.y * v1.y + zv.z * v1.z + zv.w * v1.w;
        a2 += zv.x * v2.x + zv.y * v2.y + zv.z * v2.z + zv.w * v2.w;
    }
    part[kp][0][c][b] = a0;
    part[kp][1][c][b] = a1;
    part[kp][2][c][b] = a2;
    __syncthreads();
    if (kp == 0) {
        float gr  = part[0][0][c][b] + part[1][0][c][b] + part[2][0][c][b];
        float gz  = part[0][1][c][b] + part[1][1][c][b] + part[2][1][c][b];
        float gin = part[0][2][c][b];
        float ghn = part[1][2][c][b] + part[2][2][c][b];
        float r  = 1.f / (1.f + expf(-(gr + bih[cg] + bhh[cg])));
        float zg = 1.f / (1.f + expf(-(gz + bih[HH + cg] + bhh[HH + cg])));
        float n  = tanhf(gin + bih[2 * HH + cg] + r * (ghn + bhh[2 * HH + cg]));
        float hp = z[b][256 + cg];
        h_out[(bg0 + b) * HH + cg] = (1.f - zg) * n + zg * hp;
    }
}

__global__ __launch_bounds__(768) void k_gru(
    const float* __restrict__ emb, const int* __restrict__ tok, int sos,
    const float* __restrict__ Wih, const float* __restrict__ Whh,
    const float* __restrict__ bih, const float* __restrict__ bhh,
    const float* __restrict__ h_in, float* __restrict__ h_out)
{
    __shared__ float z[16][772];
    __shared__ float part[3][3][16][16];
    gru_step_body(emb, tok, sos, Wih, Whh, bih, bhh, h_in, h_out,
                  z, part, threadIdx.x, blockIdx.x & 31, (blockIdx.x >> 5) * 16);
}

// ==================== output path ====================
__global__ __launch_bounds__(256) void k_outemb(
    const float* __restrict__ Hall, const float* __restrict__ preW,
    const float* __restrict__ preb, float* __restrict__ OE)
{
    __shared__ float hs[16][516];
    const int tid = threadIdx.x;
    const int c0 = blockIdx.x * 64;
    const int r0 = blockIdx.y * 16;
    #pragma unroll
    for (int i = 0; i < 8; ++i) {
        int idx = tid + i * 256;
        int rr = idx >> 7, k4 = idx & 127;
        *(float4*)&hs[rr][k4 * 4] = *(const float4*)(Hall + (size_t)(r0 + rr) * HH + k4 * 4);
    }
    __syncthreads();
    const int rr = tid & 15, cc = tid >> 4;
    int cj[4]; float acc[4];
    #pragma unroll
    for (int j = 0; j < 4; ++j) { cj[j] = c0 + cc + 16 * j; acc[j] = preb[cj[j]]; }
    for (int k4 = 0; k4 < 128; ++k4) {
        float4 hv = *(const float4*)&hs[rr][k4 * 4];
        #pragma unroll
        for (int j = 0; j < 4; ++j) {
            float4 wv = *(const float4*)(preW + (size_t)cj[j] * HH + k4 * 4);
            acc[j] += hv.x * wv.x + hv.y * wv.y + hv.z * wv.z + hv.w * wv.w;
        }
    }
    #pragma unroll
    for (int j = 0; j < 4; ++j) OE[(size_t)(r0 + rr) * EE + cj[j]] = acc[j];
}

// Fused logits + online-softmax partials. 256 thr, 64R x 256C tile, K-chunked
// both operands (23.5 KB LDS -> ~6 blocks/CU vs old 1-2). Thread tile 8x8.
__global__ __launch_bounds__(256) void k_logits(
    const float* __restrict__ OE, const float* __restrict__ emb,
    const float* __restrict__ outb, const int* __restrict__ tgt,
    float* __restrict__ m_arr, float* __restrict__ z_arr,
    unsigned int* __restrict__ am_arr, float* __restrict__ gold_arr)
{
    __shared__ float oes[64][20];      // pitch 20: 80B rows keep float4 aligned
    __shared__ float ems[256][18];     // pitch 18: float2-aligned, 2-way banks (free)
    const int tid = threadIdx.x;
    const int c0 = blockIdx.x * 256;
    const int r0 = blockIdx.y * 64;
    const int rr  = tid >> 5;          // 8 row-groups of 8 rows
    const int ccg = tid & 31;          // cols ccg + 32j

    float acc[8][8];
    #pragma unroll
    for (int i = 0; i < 8; ++i)
        #pragma unroll
        for (int j = 0; j < 8; ++j) acc[i][j] = 0.f;

    for (int kc = 0; kc < 16; ++kc) {
        __syncthreads();               // prev-chunk reads done
        {   // stage OE chunk: 64 rows x 16 k = 256 f4, one per thread
            int row = tid >> 2, f4 = tid & 3;
            *(float4*)&oes[row][f4 * 4] =
                *(const float4*)(OE + (size_t)(r0 + row) * EE + kc * 16 + f4 * 4);
        }
        #pragma unroll
        for (int i = 0; i < 8; ++i) {  // stage emb chunk: 256 cols x 16 k, f2 x8/thread
            int idx = tid + i * 256;
            int col = idx >> 3, f2 = idx & 7;
            *(float2*)&ems[col][f2 * 2] =
                *(const float2*)(emb + (size_t)(c0 + col) * EE + kc * 16 + f2 * 2);
        }
        __syncthreads();
        #pragma unroll
        for (int kk = 0; kk < 16; kk += 4) {
            float4 ov[8];
            #pragma unroll
            for (int i = 0; i < 8; ++i) ov[i] = *(const float4*)&oes[rr * 8 + i][kk];
            #pragma unroll
            for (int j = 0; j < 8; ++j) {
                float2 e0 = *(const float2*)&ems[ccg + 32 * j][kk];
                float2 e1 = *(const float2*)&ems[ccg + 32 * j][kk + 2];
                #pragma unroll
                for (int i = 0; i < 8; ++i)
                    acc[i][j] += ov[i].x * e0.x + ov[i].y * e0.y + ov[i].z * e1.x + ov[i].w * e1.y;
            }
        }
    }

    #pragma unroll
    for (int i = 0; i < 8; ++i) {
        int r = r0 + rr * 8 + i;
        int gold = tgt[r];
        float vals[8]; float m = -3.4e38f; int cb = 0x7fffffff;
        #pragma unroll
        for (int j = 0; j < 8; ++j) {
            int cj = c0 + ccg + 32 * j;
            float v = acc[i][j] + outb[cj];
            vals[j] = v;
            if (v > m) { m = v; cb = cj; }
            if (cj == gold) gold_arr[r] = v;
        }
        for (int mk = 1; mk <= 16; mk <<= 1) {
            float mo = __shfl_xor(m, mk);
            int   co = __shfl_xor(cb, mk);
            if (mo > m || (mo == m && co < cb)) { m = mo; cb = co; }
        }
        float s = 0.f;
        #pragma unroll
        for (int j = 0; j < 8; ++j) s += expf(vals[j] - m);
        for (int mk = 1; mk <= 16; mk <<= 1) s += __shfl_xor(s, mk);
        if (ccg == 0) {
            size_t p = (size_t)blockIdx.x * 3200 + r;
            m_arr[p] = m; z_arr[p] = s; am_arr[p] = (unsigned)cb;
        }
    }
}

__global__ __launch_bounds__(256) void k_merge(
    const float* __restrict__ m_arr, const float* __restrict__ z_arr,
    const unsigned* __restrict__ am_arr, const float* __restrict__ gold_arr,
    float* __restrict__ nll, float* __restrict__ out)
{
    int r = blockIdx.x * 256 + threadIdx.x;
    if (r >= 3200) return;
    float M = -3.4e38f, Z = 0.f, bm = -3.4e38f; unsigned bc = 0u;
    for (int s = 0; s < 125; ++s) {
        size_t p = (size_t)s * 3200 + r;
        float ms = m_arr[p]; float zs = z_arr[p]; unsigned cs = am_arr[p];
        if (ms > M) { Z = Z * expf(M - ms) + zs; M = ms; }
        else        { Z += zs * expf(ms - M); }
        if (ms > bm || (ms == bm && cs < bc)) { bm = ms; bc = cs; }
    }
    float pg = expf(gold_arr[r] - M) / Z;
    nll[r] = -logf(pg + 1e-20f);
    out[r] = (float)bc;
}

__global__ __launch_bounds__(128) void k_loss(
    const float* __restrict__ nll, const int* __restrict__ tgt, float* __restrict__ out)
{
    __shared__ float ls[128];
    int t = threadIdx.x;
    float lt = 0.f;
    if (t < TT) {
        float s = 0.f; int cnt = 0;
        for (int b = 0; b < BB; ++b) {
            int g = tgt[t * BB + b];
            if (g != 0) { s += nll[t * BB + b]; cnt++; }
        }
        lt = s / fmaxf((float)cnt, 1.f);
    }
    ls[t] = lt;
    __syncthreads();
    for (int off = 64; off > 0; off >>= 1) {
        if (t < off) ls[t] += ls[t + off];
        __syncthreads();
    }
    if (t == 0) out[3200] = ls[0];
}

extern "C" void kernel_launch(void* const* d_in, const int* in_sizes, int n_in,
                              void* d_out, int out_size, void* d_ws, size_t ws_size,
                              hipStream_t stream) {
    const int*   src  = (const int*)  d_in[0];
    const int*   tgt  = (const int*)  d_in[1];
    const float* emb  = (const float*)d_in[2];
    const float* eWih = (const float*)d_in[3];
    const float* eWhh = (const float*)d_in[4];
    const float* ebih = (const float*)d_in[5];
    const float* ebhh = (const float*)d_in[6];
    const float* dWih = (const float*)d_in[7];
    const float* dWhh = (const float*)d_in[8];
    const float* dbih = (const float*)d_in[9];
    const float* dbhh = (const float*)d_in[10];
    const float* preW = (const float*)d_in[11];
    const float* preb = (const float*)d_in[12];
    const float* outb = (const float*)d_in[13];

    float* ws   = (float*)d_ws;
    float* out  = (float*)d_out;
    float* hpp  = ws + WS_HPP;
    int*   arr  = (int*)(ws + WS_ARR);
    float* Hall = ws + WS_HALL;
    float* OE   = ws + WS_OE;
    float* m_a  = ws + WS_M;
    float* z_a  = ws + WS_ZZ;
    unsigned* am_a = (unsigned*)(ws + WS_AM);
    float* gold = ws + WS_GOLD;
    float* nll  = ws + WS_NLL;

    // zero h0 + all barrier counter lines
    k_zero<<<1128, 256, 0, stream>>>(ws, 288768);

    hipError_t coop_err;
    {
        const float* emb_ = emb; const int* src_ = src; const int* tgt_ = tgt;
        const float* a3 = eWih; const float* a4 = eWhh; const float* a5 = ebih; const float* a6 = ebhh;
        const float* a7 = dWih; const float* a8 = dWhh; const float* a9 = dbih; const float* a10 = dbhh;
        float* hpp_ = hpp; float* Hall_ = Hall; int* arr_ = arr;
        void* args[] = { (void*)&emb_, (void*)&src_, (void*)&tgt_,
                         (void*)&a3, (void*)&a4, (void*)&a5, (void*)&a6,
                         (void*)&a7, (void*)&a8, (void*)&a9, (void*)&a10,
                         (void*)&hpp_, (void*)&Hall_, (void*)&arr_ };
        coop_err = hipLaunchCooperativeKernel((const void*)k_rec5, dim3(NBLK), dim3(256),
                                              args, 0, stream);
    }
    if (coop_err != hipSuccess) {
        for (int t = 0; t < SS; ++t) {
            const float* hin = hpp + (t & 1) * (BB * HH);
            float* hout      = hpp + ((t + 1) & 1) * (BB * HH);
            k_gru<<<64, 768, 0, stream>>>(emb, src + t * BB, 0,
                                          eWih, eWhh, ebih, ebhh, hin, hout);
        }
        for (int t = 0; t < TT; ++t) {
            const float* hin = (t == 0) ? hpp : (Hall + (size_t)(t - 1) * BB * HH);
            float* hout      = Hall + (size_t)t * BB * HH;
            const int* tp    = (t == 0) ? src : (tgt + (t - 1) * BB);
            k_gru<<<64, 768, 0, stream>>>(emb, tp, (t == 0) ? 1 : 0,
                                          dWih, dWhh, dbih, dbhh, hin, hout);
        }
    }

    k_outemb<<<dim3(4, 200), 256, 0, stream>>>(Hall, preW, preb, OE);
    k_logits<<<dim3(125, 50), 256, 0, stream>>>(OE, emb, outb, tgt, m_a, z_a, am_a, gold);
    k_merge<<<13, 256, 0, stream>>>(m_a, z_a, am_a, gold, nll, out);
    k_loss<<<1, 128, 0, stream>>>(nll, tgt, out);
}

// Round 10
// 7303.517 us; speedup vs baseline: 1.4220x; 1.0427x over previous
//
#include <hip/hip_runtime.h>
#include <hip/hip_cooperative_groups.h>
#include <math.h>

#define VV 32000
#define EE 256
#define HH 512
#define SS 400
#define TT 100
#define BB 32
#define NBLK 128          // producer blocks; +8 service blocks = 136 total

// ---- workspace layout (float offsets) ----
#define WS_HPP   0u            // 32768: h ping-pong
#define WS_ARR   32768u        // 128000 ints: 500 steps x 8 lines x 32-int (128B) stride
#define WS_WX    160768u       // 64 ints: [0..8) writer xcd, [8..24) valA, [24..40) valB
#define WS_XF    160832u       // 512 ints: per-writer flag at w*64
#define WS_INIT  161344u       // 64 ints: [0] A-count, [16] reader acks, [32] B-count
#define WS_XB    161408u       // 131072: 8 x 16384 floats (per-XCD h copy)
#define WS_HALL  292480u       // 1638400
#define WS_OE    1930880u      // 819200
#define WS_M     2750080u      // 400000
#define WS_ZZ    3150080u
#define WS_AM    3550080u
#define WS_GOLD  3950080u
#define WS_NLL   3953280u

__global__ __launch_bounds__(256) void k_zero(float* p, int n) {
    int i = blockIdx.x * 256 + threadIdx.x;
    if (i < n) p[i] = 0.f;
}

__device__ __forceinline__ float dot4(float4 a, float4 b) {
    return a.x * b.x + a.y * b.y + a.z * b.z + a.w * b.w;
}

// MALL-coherent float4 load: 2 x uint64 relaxed agent atomics (R9-proven).
__device__ __forceinline__ float4 ld4_coh(const float* p) {
    const unsigned long long* q = (const unsigned long long*)p;
    unsigned long long a = __hip_atomic_load(q + 0, __ATOMIC_RELAXED, __HIP_MEMORY_SCOPE_AGENT);
    unsigned long long b = __hip_atomic_load(q + 1, __ATOMIC_RELAXED, __HIP_MEMORY_SCOPE_AGENT);
    float4 v;
    v.x = __uint_as_float((unsigned)(a & 0xffffffffull));
    v.y = __uint_as_float((unsigned)(a >> 32));
    v.z = __uint_as_float((unsigned)(b & 0xffffffffull));
    v.w = __uint_as_float((unsigned)(b >> 32));
    return v;
}

// x-projection for step snext (R9-proven): h-independent, fills wait windows.
__device__ __forceinline__ void gi_compute(
    const float* __restrict__ emb, const int* __restrict__ src, const int* __restrict__ tgt,
    int phase, int snext, const float4* __restrict__ Ws4,
    float (*gi_buf)[3][4][4], int w, int bq, int b0)
{
    float acc[3][4][4];
    #pragma unroll
    for (int g = 0; g < 3; ++g)
        #pragma unroll
        for (int c = 0; c < 4; ++c)
            #pragma unroll
            for (int i = 0; i < 4; ++i) acc[g][c][i] = 0.f;
    float4 x0[4], x1[4];
    #pragma unroll
    for (int i = 0; i < 4; ++i) {
        int tk = phase ? (snext ? tgt[(snext - 1) * BB + b0 + i] : 1) : src[snext * BB + b0 + i];
        const float* xr = emb + (size_t)tk * EE + w * 4;
        x0[i] = *(const float4*)xr;
        x1[i] = *(const float4*)(xr + 128);
    }
    #pragma unroll
    for (int g = 0; g < 3; ++g)
        #pragma unroll
        for (int c = 0; c < 4; ++c) {
            float4 w0 = Ws4[(g * 4 + c) * 193 + w];
            float4 w1 = Ws4[(g * 4 + c) * 193 + w + 32];
            #pragma unroll
            for (int i = 0; i < 4; ++i)
                acc[g][c][i] += dot4(x0[i], w0) + dot4(x1[i], w1);
        }
    #pragma unroll
    for (int m = 1; m <= 16; m <<= 1)
        #pragma unroll
        for (int g = 0; g < 3; ++g)
            #pragma unroll
            for (int c = 0; c < 4; ++c)
                #pragma unroll
                for (int i = 0; i < 4; ++i)
                    acc[g][c][i] += __shfl_xor(acc[g][c][i], m);
    if (w == 0)
        #pragma unroll
        for (int g = 0; g < 3; ++g)
            #pragma unroll
            for (int c = 0; c < 4; ++c)
                *(float4*)&gi_buf[bq][g][c][0] =
                    make_float4(acc[g][c][0], acc[g][c][1], acc[g][c][2], acc[g][c][3]);
}

// ==================== persistent recurrence with XCD-local h broadcast ====================
// Blocks 0..7: service (copy h MALL -> own-XCD L2 buffer each step, flag agent-scope).
// Blocks 8..135: producers (R9 compute; h acquired from XCD-L2 via sc0, verified at
// init with 2-round clock pattern; budget fallback to R9 coherent path).
__global__ __launch_bounds__(256, 1) void k_rec6(
    const float* __restrict__ emb, const int* __restrict__ src, const int* __restrict__ tgt,
    const float* __restrict__ eWih, const float* __restrict__ eWhh,
    const float* __restrict__ ebih, const float* __restrict__ ebhh,
    const float* __restrict__ dWih, const float* __restrict__ dWhh,
    const float* __restrict__ dbih, const float* __restrict__ dbhh,
    float* __restrict__ hpp, float* __restrict__ Hall, int* __restrict__ arr,
    int* __restrict__ wx, int* __restrict__ xflag, int* __restrict__ initc,
    float* __restrict__ xbuf)
{
    __shared__ float4 Ws4[12 * 193];
    __shared__ __align__(16) float gi_buf[8][3][4][4];
    __shared__ __align__(16) float gh_buf[8][3][4][4];
    __shared__ int oksh, wssh, fastsh;
    const int tid = threadIdx.x;
    const unsigned myxcd = __builtin_amdgcn_s_getreg(63508) & 0xF;   // HW_REG_XCC_ID

    if (blockIdx.x < 8) {
        // ================= service block w =================
        const int w = blockIdx.x;
        float* xb = xbuf + (size_t)w * 16384;
        if (tid == 0) {
            unsigned long long tA = (unsigned long long)clock64();
            volatile int* vb = (volatile int*)xb;
            vb[0] = (int)tA; vb[1] = (int)(tA >> 32);
            __builtin_amdgcn_s_waitcnt(0);
            __hip_atomic_store(wx + 8 + 2 * w, (int)tA, __ATOMIC_RELAXED, __HIP_MEMORY_SCOPE_AGENT);
            __hip_atomic_store(wx + 9 + 2 * w, (int)(tA >> 32), __ATOMIC_RELAXED, __HIP_MEMORY_SCOPE_AGENT);
            __hip_atomic_store(wx + w, (int)myxcd, __ATOMIC_RELAXED, __HIP_MEMORY_SCOPE_AGENT);
            __hip_atomic_fetch_add(initc, 1, __ATOMIC_RELAXED, __HIP_MEMORY_SCOPE_AGENT);
            while (__hip_atomic_load(initc + 16, __ATOMIC_RELAXED, __HIP_MEMORY_SCOPE_AGENT) < NBLK)
                __builtin_amdgcn_s_sleep(2);
            unsigned long long tB = tA ^ 0xA5A5A5A55A5A5A5Aull;
            vb[0] = (int)tB; vb[1] = (int)(tB >> 32);
            __builtin_amdgcn_s_waitcnt(0);
            __hip_atomic_store(wx + 24 + 2 * w, (int)tB, __ATOMIC_RELAXED, __HIP_MEMORY_SCOPE_AGENT);
            __hip_atomic_store(wx + 25 + 2 * w, (int)(tB >> 32), __ATOMIC_RELAXED, __HIP_MEMORY_SCOPE_AGENT);
            __hip_atomic_fetch_add(initc + 32, 1, __ATOMIC_RELAXED, __HIP_MEMORY_SCOPE_AGENT);
        }
        __syncthreads();
        for (int s = 0; s < 499; ++s) {
            if (tid < 64) {                 // wait: all 128 producers stored h(s+1)
                const int* base = arr + (size_t)s * 256;
                for (;;) {
                    int v = 0;
                    if (tid < 8)
                        v = __hip_atomic_load(base + tid * 32,
                                              __ATOMIC_RELAXED, __HIP_MEMORY_SCOPE_AGENT);
                    v += __shfl_xor(v, 1);
                    v += __shfl_xor(v, 2);
                    v += __shfl_xor(v, 4);
                    if (__shfl(v, 0) == NBLK) break;
                    __builtin_amdgcn_s_sleep(1);
                }
            }
            __syncthreads();
            const float* hsrc = (s + 1 <= SS) ? (hpp + (size_t)((s + 1) & 1) * (BB * HH))
                                              : (Hall + (size_t)(s - SS) * (BB * HH));
            float4 tmp[16];
            #pragma unroll
            for (int k = 0; k < 16; ++k) tmp[k] = ld4_coh(hsrc + tid * 4 + k * 1024);
            #pragma unroll
            for (int k = 0; k < 16; ++k) *(float4*)(xb + tid * 4 + k * 1024) = tmp[k];
            __builtin_amdgcn_s_waitcnt(0);  // this wave's stores at L2
            __syncthreads();                // => all stores at L2
            if (tid == 0) {                 // flag: agent scope (MALL), data stays in L2
                int fv = s + 1;
                int* fp = xflag + w * 64;
                asm volatile("global_store_dword %0, %1, off sc1" :: "v"(fp), "v"(fv) : "memory");
            }
        }
        return;
    }

    // ================= producer block =================
    const int p   = blockIdx.x - 8;
    const int w   = tid & 31;
    const int bq  = tid >> 5;
    const int b0  = bq * 4;
    const int cg0 = p * 4;
    const int myline = (p & 7) * 32;

    // init: find this XCD's writer, verify L2 pathway (2 rounds)
    if (tid == 0) {
        while (__hip_atomic_load(initc, __ATOMIC_RELAXED, __HIP_MEMORY_SCOPE_AGENT) < 8)
            __builtin_amdgcn_s_sleep(2);
        int ws_ = -1;
        for (int ww = 0; ww < 8; ++ww)
            if (ws_ < 0 &&
                __hip_atomic_load(wx + ww, __ATOMIC_RELAXED, __HIP_MEMORY_SCOPE_AGENT) == (int)myxcd)
                ws_ = ww;
        int okA = 0;
        if (ws_ >= 0) {
            const float* vp = xbuf + (size_t)ws_ * 16384;
            int a, b;
            asm volatile("global_load_dword %0, %2, off sc0\n\t"
                         "global_load_dword %1, %2, off offset:4 sc0\n\t"
                         "s_waitcnt vmcnt(0)"
                         : "=&v"(a), "=&v"(b) : "v"(vp) : "memory");
            okA = (a == __hip_atomic_load(wx + 8 + 2 * ws_, __ATOMIC_RELAXED, __HIP_MEMORY_SCOPE_AGENT) &&
                   b == __hip_atomic_load(wx + 9 + 2 * ws_, __ATOMIC_RELAXED, __HIP_MEMORY_SCOPE_AGENT));
        }
        __hip_atomic_fetch_add(initc + 16, 1, __ATOMIC_RELAXED, __HIP_MEMORY_SCOPE_AGENT);
        while (__hip_atomic_load(initc + 32, __ATOMIC_RELAXED, __HIP_MEMORY_SCOPE_AGENT) < 8)
            __builtin_amdgcn_s_sleep(2);
        int okB = 0;
        if (ws_ >= 0 && okA) {
            const float* vp = xbuf + (size_t)ws_ * 16384;
            int a, b;
            asm volatile("global_load_dword %0, %2, off sc0\n\t"
                         "global_load_dword %1, %2, off offset:4 sc0\n\t"
                         "s_waitcnt vmcnt(0)"
                         : "=&v"(a), "=&v"(b) : "v"(vp) : "memory");
            okB = (a == __hip_atomic_load(wx + 24 + 2 * ws_, __ATOMIC_RELAXED, __HIP_MEMORY_SCOPE_AGENT) &&
                   b == __hip_atomic_load(wx + 25 + 2 * ws_, __ATOMIC_RELAXED, __HIP_MEMORY_SCOPE_AGENT));
        }
        wssh = ws_;
        fastsh = (ws_ >= 0) && okA && okB;
    }
    __syncthreads();
    const int  wstar   = wssh;
    const bool fast_ok = (fastsh != 0);
    const float* xb = xbuf + (size_t)(wstar < 0 ? 0 : wstar) * 16384;

    int s = 0;
    for (int phase = 0; phase < 2; ++phase) {
        const float* Wih = phase ? dWih : eWih;
        const float* Whh = phase ? dWhh : eWhh;
        const float* bih = phase ? dbih : ebih;
        const float* bhh = phase ? dbhh : ebhh;

        for (int u = tid; u < 12 * 192; u += 256) {
            int r = u / 192, q = u - r * 192;
            int g = r >> 2, c = r & 3;
            size_t row = (size_t)(g * HH + cg0 + c);
            float4 v;
            if (q < 64) v = *(const float4*)(Wih + row * EE + q * 4);
            else        v = *(const float4*)(Whh + row * HH + (q - 64) * 4);
            Ws4[r * 193 + q] = v;
        }
        float br_ = 0.f, bz_ = 0.f, bnx_ = 0.f, bnh_ = 0.f;
        if (tid < 128) {
            int cg = cg0 + (tid & 3);
            br_  = bih[cg] + bhh[cg];
            bz_  = bih[HH + cg] + bhh[HH + cg];
            bnx_ = bih[2 * HH + cg];
            bnh_ = bhh[2 * HH + cg];
        }
        __syncthreads();
        gi_compute(emb, src, tgt, phase, 0, Ws4, gi_buf, w, bq, b0);
        __syncthreads();

        const int T = phase ? TT : SS;
        for (int t = 0; t < T; ++t, ++s) {
            const float* hprev; float* hnext;
            if (phase == 0) {
                hprev = hpp + (t & 1) * (BB * HH);
                hnext = hpp + ((t + 1) & 1) * (BB * HH);
            } else {
                hprev = t ? (Hall + (size_t)(t - 1) * (BB * HH)) : hpp;
                hnext = Hall + (size_t)t * (BB * HH);
            }

            // ---- acquire h(s) ----
            float4 hf[4][4];
            if (s == 0) {
                #pragma unroll
                for (int i = 0; i < 4; ++i) {
                    const float* hr = hprev + (b0 + i) * HH + w * 4;
                    #pragma unroll
                    for (int jh = 0; jh < 4; ++jh) hf[i][jh] = *(const float4*)(hr + jh * 128);
                }
            } else {
                int ok = 0;
                if (fast_ok) {
                    if (tid == 0) {
                        int o = 0;
                        for (int it = 0; it < 512; ++it) {
                            if (__hip_atomic_load(xflag + wstar * 64,
                                    __ATOMIC_RELAXED, __HIP_MEMORY_SCOPE_AGENT) >= s) { o = 1; break; }
                            __builtin_amdgcn_s_sleep(1);
                        }
                        oksh = o;
                    }
                    __syncthreads();
                    ok = oksh;
                }
                if (ok) {
                    const float* q0 = xb + (b0 + 0) * HH + w * 4;
                    const float* q1 = xb + (b0 + 1) * HH + w * 4;
                    const float* q2 = xb + (b0 + 2) * HH + w * 4;
                    const float* q3 = xb + (b0 + 3) * HH + w * 4;
                    asm volatile(
                        "global_load_dwordx4 %0, %16, off sc0\n\t"
                        "global_load_dwordx4 %1, %16, off offset:512 sc0\n\t"
                        "global_load_dwordx4 %2, %16, off offset:1024 sc0\n\t"
                        "global_load_dwordx4 %3, %16, off offset:1536 sc0\n\t"
                        "global_load_dwordx4 %4, %17, off sc0\n\t"
                        "global_load_dwordx4 %5, %17, off offset:512 sc0\n\t"
                        "global_load_dwordx4 %6, %17, off offset:1024 sc0\n\t"
                        "global_load_dwordx4 %7, %17, off offset:1536 sc0\n\t"
                        "global_load_dwordx4 %8, %18, off sc0\n\t"
                        "global_load_dwordx4 %9, %18, off offset:512 sc0\n\t"
                        "global_load_dwordx4 %10, %18, off offset:1024 sc0\n\t"
                        "global_load_dwordx4 %11, %18, off offset:1536 sc0\n\t"
                        "global_load_dwordx4 %12, %19, off sc0\n\t"
                        "global_load_dwordx4 %13, %19, off offset:512 sc0\n\t"
                        "global_load_dwordx4 %14, %19, off offset:1024 sc0\n\t"
                        "global_load_dwordx4 %15, %19, off offset:1536 sc0\n\t"
                        "s_waitcnt vmcnt(0)"
                        : "=&v"(hf[0][0]), "=&v"(hf[0][1]), "=&v"(hf[0][2]), "=&v"(hf[0][3]),
                          "=&v"(hf[1][0]), "=&v"(hf[1][1]), "=&v"(hf[1][2]), "=&v"(hf[1][3]),
                          "=&v"(hf[2][0]), "=&v"(hf[2][1]), "=&v"(hf[2][2]), "=&v"(hf[2][3]),
                          "=&v"(hf[3][0]), "=&v"(hf[3][1]), "=&v"(hf[3][2]), "=&v"(hf[3][3])
                        : "v"(q0), "v"(q1), "v"(q2), "v"(q3)
                        : "memory");
                } else {
                    // fallback: R9 path — poll arrive lines of step s-1, coherent read
                    if (tid < 64) {
                        const int* base = arr + (size_t)(s - 1) * 256;
                        for (;;) {
                            int v = 0;
                            if (tid < 8)
                                v = __hip_atomic_load(base + tid * 32,
                                                      __ATOMIC_RELAXED, __HIP_MEMORY_SCOPE_AGENT);
                            v += __shfl_xor(v, 1);
                            v += __shfl_xor(v, 2);
                            v += __shfl_xor(v, 4);
                            if (__shfl(v, 0) == NBLK) break;
                            __builtin_amdgcn_s_sleep(1);
                        }
                    }
                    __syncthreads();
                    #pragma unroll
                    for (int i = 0; i < 4; ++i) {
                        const float* hr = hprev + (b0 + i) * HH + w * 4;
                        #pragma unroll
                        for (int jh = 0; jh < 4; ++jh) hf[i][jh] = ld4_coh(hr + jh * 128);
                    }
                }
            }

            // ---- gh = W_hh @ h_prev (R9-proven math) ----
            float ah[3][4][4];
            #pragma unroll
            for (int g = 0; g < 3; ++g)
                #pragma unroll
                for (int c = 0; c < 4; ++c)
                    #pragma unroll
                    for (int i = 0; i < 4; ++i) ah[g][c][i] = 0.f;
            #pragma unroll
            for (int jh = 0; jh < 4; ++jh)
                #pragma unroll
                for (int g = 0; g < 3; ++g)
                    #pragma unroll
                    for (int c = 0; c < 4; ++c) {
                        float4 wv = Ws4[(g * 4 + c) * 193 + 64 + w + 32 * jh];
                        #pragma unroll
                        for (int i = 0; i < 4; ++i)
                            ah[g][c][i] += dot4(hf[i][jh], wv);
                    }
            #pragma unroll
            for (int m = 1; m <= 16; m <<= 1)
                #pragma unroll
                for (int g = 0; g < 3; ++g)
                    #pragma unroll
                    for (int c = 0; c < 4; ++c)
                        #pragma unroll
                        for (int i = 0; i < 4; ++i)
                            ah[g][c][i] += __shfl_xor(ah[g][c][i], m);
            if (w == 0)
                #pragma unroll
                for (int g = 0; g < 3; ++g)
                    #pragma unroll
                    for (int c = 0; c < 4; ++c)
                        *(float4*)&gh_buf[bq][g][c][0] =
                            make_float4(ah[g][c][0], ah[g][c][1], ah[g][c][2], ah[g][c][3]);
            __syncthreads();

            // ---- activation + coherent h store ----
            if (tid < 128) {
                int b = tid >> 2, c = tid & 3;
                int bq2 = b >> 2, i2 = b & 3;
                float gr  = gi_buf[bq2][0][c][i2] + gh_buf[bq2][0][c][i2] + br_;
                float gz  = gi_buf[bq2][1][c][i2] + gh_buf[bq2][1][c][i2] + bz_;
                float gnx = gi_buf[bq2][2][c][i2] + bnx_;
                float gnh = gh_buf[bq2][2][c][i2] + bnh_;
                float r = 1.f / (1.f + expf(-gr));
                float z = 1.f / (1.f + expf(-gz));
                float n = tanhf(gnx + r * gnh);
                float hp = __hip_atomic_load(hprev + b * HH + cg0 + c,
                                             __ATOMIC_RELAXED, __HIP_MEMORY_SCOPE_AGENT);
                __hip_atomic_store(hnext + b * HH + cg0 + c, (1.f - z) * n + z * hp,
                                   __ATOMIC_RELAXED, __HIP_MEMORY_SCOPE_AGENT);
            }
            __builtin_amdgcn_s_waitcnt(0);
            __syncthreads();
            if (tid == 0)
                __hip_atomic_fetch_add(arr + (size_t)s * 256 + myline, 1,
                                       __ATOMIC_RELAXED, __HIP_MEMORY_SCOPE_AGENT);
            if (t < T - 1)
                gi_compute(emb, src, tgt, phase, t + 1, Ws4, gi_buf, w, bq, b0);
            __syncthreads();
        }
    }
}

// ==================== R1-proven fallback (per-step launches) ====================
__device__ __forceinline__ void gru_step_body(
    const float* __restrict__ emb, const int* __restrict__ tok, int sos,
    const float* __restrict__ Wih, const float* __restrict__ Whh,
    const float* __restrict__ bih, const float* __restrict__ bhh,
    const float* __restrict__ h_in, float* __restrict__ h_out,
    float (*z)[772], float (*part)[3][16][16],
    int tid, int cblk, int bg0)
{
    #pragma unroll
    for (int i = 0; i < 4; ++i) {
        int idx = tid + i * 768;
        if (idx < 1024) {
            int bl = idx >> 6, k4 = idx & 63;
            int tk = sos ? 1 : tok[bg0 + bl];
            *(float4*)&z[bl][k4 * 4] = *(const float4*)(emb + (size_t)tk * EE + k4 * 4);
        } else {
            int j = idx - 1024;
            int bl = j >> 7, k4 = j & 127;
            *(float4*)&z[bl][256 + k4 * 4] = *(const float4*)(h_in + (bg0 + bl) * HH + k4 * 4);
        }
    }
    __syncthreads();
    const int b  = tid & 15;
    const int c  = (tid >> 4) & 15;
    const int kp = tid >> 8;
    const int cg = cblk * 16 + c;
    const float *w0, *w1, *w2; int koff;
    if (kp == 0) {
        w0 = Wih + (size_t)(0 * HH + cg) * EE;
        w1 = Wih + (size_t)(1 * HH + cg) * EE;
        w2 = Wih + (size_t)(2 * HH + cg) * EE;
        koff = 0;
    } else {
        int o = (kp == 1) ? 0 : 256;
        w0 = Whh + (size_t)(0 * HH + cg) * HH + o;
        w1 = Whh + (size_t)(1 * HH + cg) * HH + o;
        w2 = Whh + (size_t)(2 * HH + cg) * HH + o;
        koff = 256 + o;
    }
    float a0 = 0.f, a1 = 0.f, a2 = 0.f;
    #pragma unroll 8
    for (int k4 = 0; k4 < 64; ++k4) {
        float4 zv = *(const float4*)&z[b][koff + k4 * 4];
        float4 v0 = *(const float4*)(w0 + k4 * 4);
        float4 v1 = *(const float4*)(w1 + k4 * 4);
        float4 v2 = *(const float4*)(w2 + k4 * 4);
        a0 += zv.x * v0.x + zv.y * v0.y + zv.z * v0.z + zv.w * v0.w;
        a1 += zv.x * v1.x + zv.y * v1.y + zv.z * v1.z + zv.w * v1.w;
        a2 += zv.x * v2.x + zv.y * v2.y + zv.z * v2.z + zv.w * v2.w;
    }
    part[kp][0][c][b] = a0;
    part[kp][1][c][b] = a1;
    part[kp][2][c][b] = a2;
    __syncthreads();
    if (kp == 0) {
        float gr  = part[0][0][c][b] + part[1][0][c][b] + part[2][0][c][b];
        float gz  = part[0][1][c][b] + part[1][1][c][b] + part[2][1][c][b];
        float gin = part[0][2][c][b];
        float ghn = part[1][2][c][b] + part[2][2][c][b];
        float r  = 1.f / (1.f + expf(-(gr + bih[cg] + bhh[cg])));
        float zg = 1.f / (1.f + expf(-(gz + bih[HH + cg] + bhh[HH + cg])));
        float n  = tanhf(gin + bih[2 * HH + cg] + r * (ghn + bhh[2 * HH + cg]));
        float hp = z[b][256 + cg];
        h_out[(bg0 + b) * HH + cg] = (1.f - zg) * n + zg * hp;
    }
}

__global__ __launch_bounds__(768) void k_gru(
    const float* __restrict__ emb, const int* __restrict__ tok, int sos,
    const float* __restrict__ Wih, const float* __restrict__ Whh,
    const float* __restrict__ bih, const float* __restrict__ bhh,
    const float* __restrict__ h_in, float* __restrict__ h_out)
{
    __shared__ float z[16][772];
    __shared__ float part[3][3][16][16];
    gru_step_body(emb, tok, sos, Wih, Whh, bih, bhh, h_in, h_out,
                  z, part, threadIdx.x, blockIdx.x & 31, (blockIdx.x >> 5) * 16);
}

// ==================== output path (R9-proven, unchanged) ====================
__global__ __launch_bounds__(256) void k_outemb(
    const float* __restrict__ Hall, const float* __restrict__ preW,
    const float* __restrict__ preb, float* __restrict__ OE)
{
    __shared__ float hs[16][516];
    const int tid = threadIdx.x;
    const int c0 = blockIdx.x * 64;
    const int r0 = blockIdx.y * 16;
    #pragma unroll
    for (int i = 0; i < 8; ++i) {
        int idx = tid + i * 256;
        int rr = idx >> 7, k4 = idx & 127;
        *(float4*)&hs[rr][k4 * 4] = *(const float4*)(Hall + (size_t)(r0 + rr) * HH + k4 * 4);
    }
    __syncthreads();
    const int rr = tid & 15, cc = tid >> 4;
    int cj[4]; float acc[4];
    #pragma unroll
    for (int j = 0; j < 4; ++j) { cj[j] = c0 + cc + 16 * j; acc[j] = preb[cj[j]]; }
    for (int k4 = 0; k4 < 128; ++k4) {
        float4 hv = *(const float4*)&hs[rr][k4 * 4];
        #pragma unroll
        for (int j = 0; j < 4; ++j) {
            float4 wv = *(const float4*)(preW + (size_t)cj[j] * HH + k4 * 4);
            acc[j] += hv.x * wv.x + hv.y * wv.y + hv.z * wv.z + hv.w * wv.w;
        }
    }
    #pragma unroll
    for (int j = 0; j < 4; ++j) OE[(size_t)(r0 + rr) * EE + cj[j]] = acc[j];
}

__global__ __launch_bounds__(256) void k_logits(
    const float* __restrict__ OE, const float* __restrict__ emb,
    const float* __restrict__ outb, const int* __restrict__ tgt,
    float* __restrict__ m_arr, float* __restrict__ z_arr,
    unsigned int* __restrict__ am_arr, float* __restrict__ gold_arr)
{
    __shared__ float oes[64][20];
    __shared__ float ems[256][18];
    const int tid = threadIdx.x;
    const int c0 = blockIdx.x * 256;
    const int r0 = blockIdx.y * 64;
    const int rr  = tid >> 5;
    const int ccg = tid & 31;

    float acc[8][8];
    #pragma unroll
    for (int i = 0; i < 8; ++i)
        #pragma unroll
        for (int j = 0; j < 8; ++j) acc[i][j] = 0.f;

    for (int kc = 0; kc < 16; ++kc) {
        __syncthreads();
        {
            int row = tid >> 2, f4 = tid & 3;
            *(float4*)&oes[row][f4 * 4] =
                *(const float4*)(OE + (size_t)(r0 + row) * EE + kc * 16 + f4 * 4);
        }
        #pragma unroll
        for (int i = 0; i < 8; ++i) {
            int idx = tid + i * 256;
            int col = idx >> 3, f2 = idx & 7;
            *(float2*)&ems[col][f2 * 2] =
                *(const float2*)(emb + (size_t)(c0 + col) * EE + kc * 16 + f2 * 2);
        }
        __syncthreads();
        #pragma unroll
        for (int kk = 0; kk < 16; kk += 4) {
            float4 ov[8];
            #pragma unroll
            for (int i = 0; i < 8; ++i) ov[i] = *(const float4*)&oes[rr * 8 + i][kk];
            #pragma unroll
            for (int j = 0; j < 8; ++j) {
                float2 e0 = *(const float2*)&ems[ccg + 32 * j][kk];
                float2 e1 = *(const float2*)&ems[ccg + 32 * j][kk + 2];
                #pragma unroll
                for (int i = 0; i < 8; ++i)
                    acc[i][j] += ov[i].x * e0.x + ov[i].y * e0.y + ov[i].z * e1.x + ov[i].w * e1.y;
            }
        }
    }

    #pragma unroll
    for (int i = 0; i < 8; ++i) {
        int r = r0 + rr * 8 + i;
        int gold = tgt[r];
        float vals[8]; float m = -3.4e38f; int cb = 0x7fffffff;
        #pragma unroll
        for (int j = 0; j < 8; ++j) {
            int cj = c0 + ccg + 32 * j;
            float v = acc[i][j] + outb[cj];
            vals[j] = v;
            if (v > m) { m = v; cb = cj; }
            if (cj == gold) gold_arr[r] = v;
        }
        for (int mk = 1; mk <= 16; mk <<= 1) {
            float mo = __shfl_xor(m, mk);
            int   co = __shfl_xor(cb, mk);
            if (mo > m || (mo == m && co < cb)) { m = mo; cb = co; }
        }
        float s = 0.f;
        #pragma unroll
        for (int j = 0; j < 8; ++j) s += expf(vals[j] - m);
        for (int mk = 1; mk <= 16; mk <<= 1) s += __shfl_xor(s, mk);
        if (ccg == 0) {
            size_t p = (size_t)blockIdx.x * 3200 + r;
            m_arr[p] = m; z_arr[p] = s; am_arr[p] = (unsigned)cb;
        }
    }
}

__global__ __launch_bounds__(256) void k_merge(
    const float* __restrict__ m_arr, const float* __restrict__ z_arr,
    const unsigned* __restrict__ am_arr, const float* __restrict__ gold_arr,
    float* __restrict__ nll, float* __restrict__ out)
{
    int r = blockIdx.x * 256 + threadIdx.x;
    if (r >= 3200) return;
    float M = -3.4e38f, Z = 0.f, bm = -3.4e38f; unsigned bc = 0u;
    for (int s = 0; s < 125; ++s) {
        size_t p = (size_t)s * 3200 + r;
        float ms = m_arr[p]; float zs = z_arr[p]; unsigned cs = am_arr[p];
        if (ms > M) { Z = Z * expf(M - ms) + zs; M = ms; }
        else        { Z += zs * expf(ms - M); }
        if (ms > bm || (ms == bm && cs < bc)) { bm = ms; bc = cs; }
    }
    float pg = expf(gold_arr[r] - M) / Z;
    nll[r] = -logf(pg + 1e-20f);
    out[r] = (float)bc;
}

__global__ __launch_bounds__(128) void k_loss(
    const float* __restrict__ nll, const int* __restrict__ tgt, float* __restrict__ out)
{
    __shared__ float ls[128];
    int t = threadIdx.x;
    float lt = 0.f;
    if (t < TT) {
        float s = 0.f; int cnt = 0;
        for (int b = 0; b < BB; ++b) {
            int g = tgt[t * BB + b];
            if (g != 0) { s += nll[t * BB + b]; cnt++; }
        }
        lt = s / fmaxf((float)cnt, 1.f);
    }
    ls[t] = lt;
    __syncthreads();
    for (int off = 64; off > 0; off >>= 1) {
        if (t < off) ls[t] += ls[t + off];
        __syncthreads();
    }
    if (t == 0) out[3200] = ls[0];
}

extern "C" void kernel_launch(void* const* d_in, const int* in_sizes, int n_in,
                              void* d_out, int out_size, void* d_ws, size_t ws_size,
                              hipStream_t stream) {
    const int*   src  = (const int*)  d_in[0];
    const int*   tgt  = (const int*)  d_in[1];
    const float* emb  = (const float*)d_in[2];
    const float* eWih = (const float*)d_in[3];
    const float* eWhh = (const float*)d_in[4];
    const float* ebih = (const float*)d_in[5];
    const float* ebhh = (const float*)d_in[6];
    const float* dWih = (const float*)d_in[7];
    const float* dWhh = (const float*)d_in[8];
    const float* dbih = (const float*)d_in[9];
    const float* dbhh = (const float*)d_in[10];
    const float* preW = (const float*)d_in[11];
    const float* preb = (const float*)d_in[12];
    const float* outb = (const float*)d_in[13];

    float* ws   = (float*)d_ws;
    float* out  = (float*)d_out;
    float* hpp  = ws + WS_HPP;
    int*   arr  = (int*)(ws + WS_ARR);
    int*   wx   = (int*)(ws + WS_WX);
    int*   xfl  = (int*)(ws + WS_XF);
    int*   ini  = (int*)(ws + WS_INIT);
    float* xbuf = ws + WS_XB;
    float* Hall = ws + WS_HALL;
    float* OE   = ws + WS_OE;
    float* m_a  = ws + WS_M;
    float* z_a  = ws + WS_ZZ;
    unsigned* am_a = (unsigned*)(ws + WS_AM);
    float* gold = ws + WS_GOLD;
    float* nll  = ws + WS_NLL;

    // zero h0 + arrive lines + wx + flags + init counters
    k_zero<<<631, 256, 0, stream>>>(ws, 161408);

    hipError_t coop_err;
    {
        const float* emb_ = emb; const int* src_ = src; const int* tgt_ = tgt;
        const float* a3 = eWih; const float* a4 = eWhh; const float* a5 = ebih; const float* a6 = ebhh;
        const float* a7 = dWih; const float* a8 = dWhh; const float* a9 = dbih; const float* a10 = dbhh;
        float* hpp_ = hpp; float* Hall_ = Hall; int* arr_ = arr;
        int* wx_ = wx; int* xfl_ = xfl; int* ini_ = ini; float* xbuf_ = xbuf;
        void* args[] = { (void*)&emb_, (void*)&src_, (void*)&tgt_,
                         (void*)&a3, (void*)&a4, (void*)&a5, (void*)&a6,
                         (void*)&a7, (void*)&a8, (void*)&a9, (void*)&a10,
                         (void*)&hpp_, (void*)&Hall_, (void*)&arr_,
                         (void*)&wx_, (void*)&xfl_, (void*)&ini_, (void*)&xbuf_ };
        coop_err = hipLaunchCooperativeKernel((const void*)k_rec6, dim3(NBLK + 8), dim3(256),
                                              args, 0, stream);
    }
    if (coop_err != hipSuccess) {
        for (int t = 0; t < SS; ++t) {
            const float* hin = hpp + (t & 1) * (BB * HH);
            float* hout      = hpp + ((t + 1) & 1) * (BB * HH);
            k_gru<<<64, 768, 0, stream>>>(emb, src + t * BB, 0,
                                          eWih, eWhh, ebih, ebhh, hin, hout);
        }
        for (int t = 0; t < TT; ++t) {
            const float* hin = (t == 0) ? hpp : (Hall + (size_t)(t - 1) * BB * HH);
            float* hout      = Hall + (size_t)t * BB * HH;
            const int* tp    = (t == 0) ? src : (tgt + (t - 1) * BB);
            k_gru<<<64, 768, 0, stream>>>(emb, tp, (t == 0) ? 1 : 0,
                                          dWih, dWhh, dbih, dbhh, hin, hout);
        }
    }

    k_outemb<<<dim3(4, 200), 256, 0, stream>>>(Hall, preW, preb, OE);
    k_logits<<<dim3(125, 50), 256, 0, stream>>>(OE, emb, outb, tgt, m_a, z_a, am_a, gold);
    k_merge<<<13, 256, 0, stream>>>(m_a, z_a, am_a, gold, nll, out);
    k_loss<<<1, 128, 0, stream>>>(nll, tgt, out);
}